// Round 7
// baseline (497.978 us; speedup 1.0000x reference)
//
#include <hip/hip_runtime.h>

typedef _Float16 f16;
typedef _Float16 f16x8 __attribute__((ext_vector_type(8)));
typedef float f32x4 __attribute__((ext_vector_type(4)));

#define LN4 1.3862943611198906f

// ===========================================================================
// Weight prep.
// 3-term layout: WT[d][tap][ h(CIN) | l(CIN) ] f16, d<CPAD, tap<28.
// plain layout:  WT[d][tap][ h(CIN) ] f16.
// ===========================================================================
__device__ void prep_split(int gid, int gsz, const float* __restrict__ W,
                           f16* __restrict__ dst, int CIN, int COUT, int CPAD)
{
    int total = CPAD * 28 * CIN;
    for (int i = gid; i < total; i += gsz) {
        int d = i / (28 * CIN);
        int rem = i - d * (28 * CIN);
        int tap = rem / CIN;
        int c = rem - tap * CIN;
        float v = (d < COUT && tap < 27) ? W[(size_t)(tap * CIN + c) * COUT + d] : 0.f;
        f16 h = (f16)v;
        size_t base = (size_t)d * (28 * 2 * CIN) + (size_t)tap * (2 * CIN);
        dst[base + c] = h;
        dst[base + CIN + c] = (f16)(v - (float)h);
    }
}

__device__ void prep_plain16(int gid, int gsz, const float* __restrict__ W,
                             f16* __restrict__ dst, int COUT)
{
    const int CIN = 16, CPAD = 16;
    int total = CPAD * 28 * CIN;
    for (int i = gid; i < total; i += gsz) {
        int d = i / (28 * CIN);
        int rem = i - d * (28 * CIN);
        int tap = rem / CIN;
        int c = rem - tap * CIN;
        float v = (d < COUT && tap < 27) ? W[(size_t)(tap * CIN + c) * COUT + d] : 0.f;
        dst[(size_t)d * (28 * CIN) + (size_t)tap * CIN + c] = (f16)v;
    }
}

__device__ void prep_pts(int gid, int gsz, const float* __restrict__ Wp,
                         const float* __restrict__ Ws, const float* __restrict__ Wt,
                         f16* __restrict__ dst)
{
    const int CIN = 16, CPAD = 16;
    int total = CPAD * 28 * CIN;
    for (int i = gid; i < total; i += gsz) {
        int d = i / (28 * CIN);
        int rem = i - d * (28 * CIN);
        int tap = rem / CIN;
        int c = rem - tap * CIN;
        float v = 0.f;
        if (tap < 27) {
            int kc = tap * CIN + c;
            if (d < 3)       v = Wp[(size_t)kc * 3 + d];
            else if (d < 5)  v = Ws[(size_t)kc * 2 + (d - 3)];
            else if (d < 10) v = Wt[(size_t)kc * 5 + (d - 5)];
        }
        dst[(size_t)d * (28 * CIN) + (size_t)tap * CIN + c] = (f16)v;
    }
}

__global__ __launch_bounds__(256) void prep_all_kernel(
    const float* W1, f16* WT1, const float* W2, f16* WT2,
    const float* W3, f16* WT3,
    const float* W3p, const float* W3s, const float* W3t, f16* WTp)
{
    int gid = blockIdx.x * 256 + threadIdx.x;
    int gsz = gridDim.x * 256;
    prep_split(gid, gsz, W1, WT1, 80, 80, 80);
    prep_split(gid, gsz, W2, WT2, 48, 48, 48);
    prep_plain16(gid, gsz, W3, WT3, 16);
    prep_pts(gid, gsz, W3p, W3s, W3t, WTp);
}

// ===========================================================================
// Feature splits. 3-term: rows [h|l]; plain: rows [h]. Sentinel row at n==N.
// ===========================================================================
template<int CIN, bool SPLIT>
__global__ __launch_bounds__(256) void split_feat_kernel(
    const float* __restrict__ f, const float* __restrict__ mask,
    const int* __restrict__ parent, f16* __restrict__ Fc, int N)
{
    int i = blockIdx.x * 256 + threadIdx.x;
    if (i >= (N + 1) * CIN) return;
    int n = i / CIN;
    int c = i - n * CIN;
    float v = 0.f;
    if (n < N) {
        v = f[i];
        if (mask != nullptr) v *= mask[parent[n]];
    }
    if (SPLIT) {
        f16 h = (f16)v;
        Fc[(size_t)n * (2 * CIN) + c] = h;
        Fc[(size_t)n * (2 * CIN) + CIN + c] = (f16)(v - (float)h);
    } else {
        Fc[(size_t)n * CIN + c] = (f16)v;
    }
}

__global__ __launch_bounds__(256) void ppn_finalize_kernel(
    const int* __restrict__ coords, const float* __restrict__ s,
    float* __restrict__ ppn, float* __restrict__ mask, int N)
{
    int n = blockIdx.x * 256 + threadIdx.x;
    if (n >= N) return;
    float s0 = s[(size_t)n * 2 + 0], s1 = s[(size_t)n * 2 + 1];
    ppn[(size_t)n * 6 + 0] = (float)coords[(size_t)n * 4 + 0];
    ppn[(size_t)n * 6 + 1] = (float)coords[(size_t)n * 4 + 1];
    ppn[(size_t)n * 6 + 2] = (float)coords[(size_t)n * 4 + 2];
    ppn[(size_t)n * 6 + 3] = (float)coords[(size_t)n * 4 + 3];
    ppn[(size_t)n * 6 + 4] = s0;
    ppn[(size_t)n * 6 + 5] = s1;
    mask[n] = (s1 - s0 > LN4) ? 1.0f : 0.0f;
}

// ===========================================================================
// MFMA gather-conv, VGPR round-trip staging (COALESCED requests).
// Key: TA issues ~1 request/cyc/CU; uncoalesced 16B requests (global_load_lds,
// or per-lane gathers with row-per-lane layout) were the R3-R6 bound. Here
// adjacent lanes load adjacent 16B chunks of the same tap-row -> TA merges
// each row into ~3 wide requests.
// Pipeline per 2-tap slab p (single LDS buffer, latency fully covered):
//   global loads(p+1) -> VGPR ; compute(p) from LDS ; bar ; ds_write(p+1) ; bar
// BWHOLE: B (tiny, L3) staged once in prologue; only A cycles.
// Pitch-padded LDS (+1 chunk/row -> bank stride 4 mod 32, 2-way = free).
// Epilogues: F16 (+sentinel row), F32 (cols<OUTC), SCAT (fused score conv via
// symmetric scatter, guarded atomics: sentinel atomics serialize the device!).
// ===========================================================================
enum { EPI_F16 = 1, EPI_F32 = 2, EPI_SCAT = 3 };

template<int CIN, int NCT, int NTERMS, int NW, int EPI, int OUTC, bool BWHOLE, int MINW>
__global__ __launch_bounds__(NW * 64, MINW) void conv_rt(
    const f16* __restrict__ F, const int* __restrict__ nbr,
    const f16* __restrict__ WT, float* __restrict__ outf,
    f16* __restrict__ oc, const float* __restrict__ Wsc,
    float* __restrict__ sout, int N, int nTiles)
{
    constexpr int BM = NW * 16;
    constexpr int BLK = NW * 64;
    constexpr int RE = (NTERMS == 3 ? 2 : 1) * CIN;   // f16 elems per tap-row
    constexpr int RB = 2 * RE;                        // bytes per tap-row
    constexpr int CPT = RB / 16;                      // 16B chunks per tap-row
    constexpr int CPR = 2 * CPT;                      // chunks per slab-row (2 taps)
    constexpr int KB = (2 * CIN) / 32;                // K32 MFMA blocks per slab
    constexpr int COUT = NCT * 16;
    constexpr int AP = CPR + 1;                       // A LDS pitch (chunks)
    constexpr int BP = BWHOLE ? (14 * CPR + 1) : (CPR + 1);
    constexpr int ACH = BM * CPR;
    constexpr int BCH = BWHOLE ? COUT * 28 * CPT : COUT * CPR;
    constexpr int AIT = (ACH + BLK - 1) / BLK;
    constexpr int BIT = (BCH + BLK - 1) / BLK;

    __shared__ __align__(16) f16 AS[BM * AP * 8];
    __shared__ __align__(16) f16 BS[COUT * BP * 8];

    const int t = threadIdx.x;
    const int lane = t & 63;
    const int l16 = lane & 15;
    const int quad = lane >> 4;
    const int wv = t >> 6;

    int q8 = (nTiles + 7) >> 3;
    int tile = (blockIdx.x & 7) * q8 + (blockIdx.x >> 3);
    if (tile >= nTiles) return;
    const int m0 = tile * BM;

    f16x8 aT[AIT];
    f16x8 bT[BIT];

    auto loadA = [&](int p) {
        #pragma unroll
        for (int j = 0; j < AIT; ++j) {
            int i = t + j * BLK;
            if (AIT * BLK > ACH && i >= ACH) continue;
            int r = i / CPR, cs = i - r * CPR;
            int tp = cs >= CPT;
            int cc = cs - (tp ? CPT : 0);
            int row = m0 + r;
            int tap = 2 * p + tp;
            int idx = (row < N && tap < 27) ? nbr[(size_t)row * 27 + tap] : N;
            aT[j] = *(const f16x8*)((const char*)F + (size_t)idx * RB + cc * 16);
        }
    };
    auto writeA = [&]() {
        #pragma unroll
        for (int j = 0; j < AIT; ++j) {
            int i = t + j * BLK;
            if (AIT * BLK > ACH && i >= ACH) continue;
            int r = i / CPR, cs = i - r * CPR;
            *(f16x8*)&AS[(size_t)(r * AP + cs) * 8] = aT[j];
        }
    };
    auto loadB = [&](int p) {        // per-slab B
        #pragma unroll
        for (int j = 0; j < BIT; ++j) {
            int i = t + j * BLK;
            if (BIT * BLK > BCH && i >= BCH) continue;
            int d = i / CPR, cs = i - d * CPR;
            int tp = cs >= CPT;
            int cc = cs - (tp ? CPT : 0);
            bT[j] = *(const f16x8*)((const char*)WT +
                        ((size_t)d * 28 + 2 * p + tp) * RB + cc * 16);
        }
    };
    auto writeB = [&]() {
        #pragma unroll
        for (int j = 0; j < BIT; ++j) {
            int i = t + j * BLK;
            if (BIT * BLK > BCH && i >= BCH) continue;
            int d = i / CPR, cs = i - d * CPR;
            *(f16x8*)&BS[(size_t)(d * BP + cs) * 8] = bT[j];
        }
    };
    auto loadBW = [&]() {            // whole B (L3): [d][tap][CPT] linear
        #pragma unroll
        for (int j = 0; j < BIT; ++j) {
            int i = t + j * BLK;
            if (BIT * BLK > BCH && i >= BCH) continue;
            bT[j] = *(const f16x8*)((const char*)WT + (size_t)i * 16);
        }
    };
    auto writeBW = [&]() {
        #pragma unroll
        for (int j = 0; j < BIT; ++j) {
            int i = t + j * BLK;
            if (BIT * BLK > BCH && i >= BCH) continue;
            int d = i / (28 * CPT), rm = i - d * (28 * CPT);
            *(f16x8*)&BS[(size_t)(d * BP + rm) * 8] = bT[j];
        }
    };

    f32x4 acc[NCT];
    #pragma unroll
    for (int ct = 0; ct < NCT; ++ct) acc[ct] = (f32x4){0.f, 0.f, 0.f, 0.f};

    auto compute = [&](int p) {
        const int arow = wv * 16 + l16;
        #pragma unroll
        for (int kb = 0; kb < KB; ++kb) {
            int ko = kb * 32 + quad * 8;
            int ts = ko >= CIN;
            int c2 = ko - (ts ? CIN : 0);
            int ch = ts * CPT + c2 / 8;
            f16x8 a_h = *(const f16x8*)&AS[(size_t)(arow * AP + ch) * 8];
            f16x8 a_l;
            if (NTERMS == 3)
                a_l = *(const f16x8*)&AS[(size_t)(arow * AP + ch + CPT / 2) * 8];
            #pragma unroll
            for (int ct = 0; ct < NCT; ++ct) {
                int drow = ct * 16 + l16;
                int bch = BWHOLE ? (p * CPR + ch) : ch;
                f16x8 b_h = *(const f16x8*)&BS[(size_t)(drow * BP + bch) * 8];
                acc[ct] = __builtin_amdgcn_mfma_f32_16x16x32_f16(a_h, b_h, acc[ct], 0, 0, 0);
                if (NTERMS == 3) {
                    f16x8 b_l = *(const f16x8*)&BS[(size_t)(drow * BP + bch + CPT / 2) * 8];
                    acc[ct] = __builtin_amdgcn_mfma_f32_16x16x32_f16(a_l, b_h, acc[ct], 0, 0, 0);
                    acc[ct] = __builtin_amdgcn_mfma_f32_16x16x32_f16(a_h, b_l, acc[ct], 0, 0, 0);
                }
            }
        }
    };

    // prologue
    loadA(0);
    if (BWHOLE) loadBW(); else loadB(0);
    writeA();
    if (BWHOLE) writeBW(); else writeB();
    __syncthreads();

    #pragma unroll 1
    for (int p = 0; p < 14; ++p) {
        if (p < 13) { loadA(p + 1); if (!BWHOLE) loadB(p + 1); }
        compute(p);
        __syncthreads();                 // all waves done reading LDS(p); drains loads(p+1) (covered by compute)
        if (p < 13) { writeA(); if (!BWHOLE) writeB(); }
        __syncthreads();                 // writes visible
    }

    // ---- epilogues; D: row = quad*4+reg, col = lane&15 ----
    if (EPI == EPI_SCAT) {
        #pragma unroll 1
        for (int tap = 0; tap < 27; ++tap) {
            float q0[4] = {}, q1[4] = {};
            #pragma unroll
            for (int ct = 0; ct < NCT; ++ct) {
                float2 w = ((const float2*)Wsc)[(size_t)(26 - tap) * COUT + ct * 16 + l16];
                #pragma unroll
                for (int r = 0; r < 4; ++r) {
                    q0[r] += acc[ct][r] * w.x;
                    q1[r] += acc[ct][r] * w.y;
                }
            }
            #pragma unroll
            for (int m = 1; m < 16; m <<= 1) {
                #pragma unroll
                for (int r = 0; r < 4; ++r) {
                    q0[r] += __shfl_xor(q0[r], m);
                    q1[r] += __shfl_xor(q1[r], m);
                }
            }
            if (l16 < 8) {
                int r = l16 >> 1, j = l16 & 1;
                float v0 = (r == 0) ? q0[0] : (r == 1) ? q0[1] : (r == 2) ? q0[2] : q0[3];
                float v1 = (r == 0) ? q1[0] : (r == 1) ? q1[1] : (r == 2) ? q1[2] : q1[3];
                float v = (j == 0) ? v0 : v1;
                int row = m0 + wv * 16 + quad * 4 + r;
                if (row < N) {
                    int idx = nbr[(size_t)row * 27 + tap];
                    if (idx < N)             // guard: sentinel atomics serialize!
                        atomicAdd(&sout[(size_t)idx * 2 + j], v);
                }
            }
        }
    } else {
        #pragma unroll
        for (int ct = 0; ct < NCT; ++ct) {
            int col = ct * 16 + l16;
            #pragma unroll
            for (int r = 0; r < 4; ++r) {
                int row = m0 + wv * 16 + quad * 4 + r;
                float v = acc[ct][r];
                if (EPI == EPI_F16) {
                    if (row < N) oc[(size_t)row * COUT + col] = (f16)v;
                    else if (row == N) oc[(size_t)row * COUT + col] = (f16)0.f;
                } else {  // EPI_F32
                    if (row < N && col < OUTC)
                        outf[(size_t)row * OUTC + col] = v;
                }
            }
        }
    }
}

// ===========================================================================
extern "C" void kernel_launch(void* const* d_in, const int* in_sizes, int n_in,
                              void* d_out, int out_size, void* d_ws, size_t ws_size,
                              hipStream_t stream)
{
    const float* feat1 = (const float*)d_in[0];
    const float* feat2 = (const float*)d_in[1];
    const float* feat3 = (const float*)d_in[2];
    const float* W1    = (const float*)d_in[3];
    const float* W1s   = (const float*)d_in[4];
    const float* W2    = (const float*)d_in[5];
    const float* W2s   = (const float*)d_in[6];
    const float* W3    = (const float*)d_in[7];
    const float* W3p   = (const float*)d_in[8];
    const float* W3s   = (const float*)d_in[9];
    const float* W3t   = (const float*)d_in[10];
    const int* nbr1    = (const int*)d_in[11];
    const int* nbr2    = (const int*)d_in[12];
    const int* nbr3    = (const int*)d_in[13];
    const int* parent2 = (const int*)d_in[14];
    const int* parent3 = (const int*)d_in[15];
    const int* coords1 = (const int*)d_in[16];
    const int* coords2 = (const int*)d_in[17];

    const int N1 = in_sizes[0] / 80;
    const int N2 = in_sizes[1] / 48;
    const int N3 = in_sizes[2] / 16;

    float* out = (float*)d_out;
    float* o_points = out;                              // [N3,10]
    float* o_ppn1   = o_points + (size_t)N3 * 10;       // [N1,6]
    float* o_ppn2   = o_ppn1 + (size_t)N1 * 6;          // [N2,6]
    float* o_mask1  = o_ppn2 + (size_t)N2 * 6;          // [N1]
    float* o_mask2  = o_mask1 + (size_t)N1;             // [N2]

    char* wp = (char*)d_ws;
    auto alloc = [&](size_t bytes) -> char* {
        char* r = wp; wp += (bytes + 255) & ~(size_t)255; return r;
    };
    f16* WT1 = (f16*)alloc((size_t)80 * 28 * 160 * 2);
    f16* WT2 = (f16*)alloc((size_t)48 * 28 * 96 * 2);
    f16* WT3 = (f16*)alloc((size_t)16 * 28 * 16 * 2);
    f16* WTp = (f16*)alloc((size_t)16 * 28 * 16 * 2);
    float* s1 = (float*)alloc((size_t)(N1 + 1) * 2 * 4);
    float* s2 = (float*)alloc((size_t)(N2 + 1) * 2 * 4);
    size_t fe1 = (size_t)(N1 + 1) * 160, fe2 = (size_t)(N2 + 1) * 96, fe3 = (size_t)(N3 + 1) * 16;
    size_t maxF = fe1 > fe2 ? fe1 : fe2; if (fe3 > maxF) maxF = fe3;
    f16* Fa = (f16*)alloc(maxF * 2);
    f16* Ya = (f16*)alloc(maxF * 2);

    auto cdiv = [](long long a, long long b) { return (int)((a + b - 1) / b); };
    auto grid8 = [&](int nT) { return dim3(8 * cdiv(nT, 8)); };

    prep_all_kernel<<<512, 256, 0, stream>>>(W1, WT1, W2, WT2, W3, WT3,
                                             W3p, W3s, W3t, WTp);

    // ---- level 1 (coarse, C=80): conv80 + fused scatter score -> s1 ----
    {
        int T = cdiv(N1, 64);
        split_feat_kernel<80, true><<<cdiv((size_t)(N1 + 1) * 80, 256), 256, 0, stream>>>(
            feat1, nullptr, nullptr, Fa, N1);
        hipMemsetAsync(s1, 0, (size_t)(N1 + 1) * 2 * sizeof(float), stream);
        conv_rt<80, 5, 3, 4, EPI_SCAT, 2, false, 1><<<grid8(T), 256, 0, stream>>>(
            Fa, nbr1, WT1, nullptr, nullptr, W1s, s1, N1, T);
        ppn_finalize_kernel<<<cdiv(N1, 256), 256, 0, stream>>>(coords1, s1, o_ppn1, o_mask1, N1);
    }
    // ---- level 2 (mid, C=48): conv48 + fused scatter score -> s2 ----
    {
        int T = cdiv(N2, 128);
        split_feat_kernel<48, true><<<cdiv((size_t)(N2 + 1) * 48, 256), 256, 0, stream>>>(
            feat2, o_mask1, parent2, Fa, N2);
        hipMemsetAsync(s2, 0, (size_t)(N2 + 1) * 2 * sizeof(float), stream);
        conv_rt<48, 3, 3, 8, EPI_SCAT, 2, false, 4><<<grid8(T), 512, 0, stream>>>(
            Fa, nbr2, WT2, nullptr, nullptr, W2s, s2, N2, T);
        ppn_finalize_kernel<<<cdiv(N2, 256), 256, 0, stream>>>(coords2, s2, o_ppn2, o_mask2, N2);
    }
    // ---- level 3 (fine, C=16): plain f16, whole-B staged once ----
    {
        int Tz = cdiv(N3 + 1, 128);
        int Tp = cdiv(N3, 128);
        split_feat_kernel<16, false><<<cdiv((size_t)(N3 + 1) * 16, 256), 256, 0, stream>>>(
            feat3, o_mask2, parent3, Fa, N3);
        conv_rt<16, 1, 1, 8, EPI_F16, 16, true, 4><<<grid8(Tz), 512, 0, stream>>>(
            Fa, nbr3, WT3, nullptr, Ya, nullptr, nullptr, N3, Tz);
        conv_rt<16, 1, 1, 8, EPI_F32, 10, true, 4><<<grid8(Tp), 512, 0, stream>>>(
            Ya, nbr3, WTp, o_points, nullptr, nullptr, nullptr, N3, Tp);
    }
}

// Round 8
// 425.189 us; speedup vs baseline: 1.1712x; 1.1712x over previous
//
#include <hip/hip_runtime.h>

typedef _Float16 f16;
typedef _Float16 f16x8 __attribute__((ext_vector_type(8)));
typedef float f32x4 __attribute__((ext_vector_type(4)));

#define LN4 1.3862943611198906f

__device__ __forceinline__ void gl_lds16(const void* g, void* l) {
    typedef unsigned int u32;
    __builtin_amdgcn_global_load_lds(
        (const __attribute__((address_space(1))) u32*)(g),
        (__attribute__((address_space(3))) u32*)(l), 16, 0, 0);
}

// ===========================================================================
// Level-1 weight prep: fp32 W1[27][80][80] -> f16 hi/lo transposed:
// WT[d][tap][ h(80) | l(80) ], d<80, tap<28 (tap 27 = zeros).
// ===========================================================================
__global__ __launch_bounds__(256) void prep_w1_kernel(
    const float* __restrict__ W, f16* __restrict__ dst)
{
    const int CIN = 80, COUT = 80;
    int total = COUT * 28 * CIN;
    for (int i = blockIdx.x * 256 + threadIdx.x; i < total; i += gridDim.x * 256) {
        int d = i / (28 * CIN);
        int rem = i - d * (28 * CIN);
        int tap = rem / CIN;
        int c = rem - tap * CIN;
        float v = (tap < 27) ? W[(size_t)(tap * CIN + c) * COUT + d] : 0.f;
        f16 h = (f16)v;
        size_t base = (size_t)d * (28 * 2 * CIN) + (size_t)tap * (2 * CIN);
        dst[base + c] = h;
        dst[base + CIN + c] = (f16)(v - (float)h);
    }
}

// Level-1 feature split: rows [h(80)|l(80)] f16, zero-sentinel row at n==N.
__global__ __launch_bounds__(256) void split80_kernel(
    const float* __restrict__ f, f16* __restrict__ Fc, int N)
{
    int i = blockIdx.x * 256 + threadIdx.x;
    if (i >= (N + 1) * 80) return;
    int n = i / 80, c = i - n * 80;
    float v = (n < N) ? f[i] : 0.f;
    f16 h = (f16)v;
    Fc[(size_t)n * 160 + c] = h;
    Fc[(size_t)n * 160 + 80 + c] = (f16)(v - (float)h);
}

__global__ __launch_bounds__(256) void ppn_finalize_kernel(
    const int* __restrict__ coords, const float* __restrict__ s,
    float* __restrict__ ppn, float* __restrict__ mask, int N)
{
    int n = blockIdx.x * 256 + threadIdx.x;
    if (n >= N) return;
    float s0 = s[(size_t)n * 2 + 0], s1 = s[(size_t)n * 2 + 1];
    ppn[(size_t)n * 6 + 0] = (float)coords[(size_t)n * 4 + 0];
    ppn[(size_t)n * 6 + 1] = (float)coords[(size_t)n * 4 + 1];
    ppn[(size_t)n * 6 + 2] = (float)coords[(size_t)n * 4 + 2];
    ppn[(size_t)n * 6 + 3] = (float)coords[(size_t)n * 4 + 3];
    ppn[(size_t)n * 6 + 4] = s0;
    ppn[(size_t)n * 6 + 5] = s1;
    mask[n] = (s1 - s0 > LN4) ? 1.0f : 0.0f;
}

// act[i] = mask[parent[i]]  (0/1 floats)
__global__ __launch_bounds__(256) void gate_kernel(
    const float* __restrict__ mask, const int* __restrict__ parent,
    float* __restrict__ act, int N)
{
    int i = blockIdx.x * 256 + threadIdx.x;
    if (i < N) act[i] = mask[parent[i]];
}

// ===========================================================================
// Level 1: MFMA conv80 (f16-split, 3-term) fused with scatter score conv.
// Structure = R5's measured kernel: per-lane A gathers, B staged per 2-tap
// slab via global_load_lds (XOR swizzle, conflict-free), 2 barriers/slab,
// A prefetched one slab ahead. LDS 51.2 KB -> 3 blocks/CU.
// ===========================================================================
__global__ __launch_bounds__(256, 3) void conv80_scat(
    const f16* __restrict__ F, const int* __restrict__ nbr,
    const f16* __restrict__ WT, const float* __restrict__ Wsc,
    float* __restrict__ sout, int N, int nTiles)
{
    constexpr int RE = 160, CPT = 20, CPR = 40, PB = 640, KB = 5, BM = 64;
    __shared__ __align__(16) char BS[80 * PB];     // 51200 B

    const int t = threadIdx.x;
    const int lane = t & 63;
    const int l16 = lane & 15;
    const int quad = lane >> 4;
    const int wv = t >> 6;

    int q8 = (nTiles + 7) >> 3;
    int tile = (blockIdx.x & 7) * q8 + (blockIdx.x >> 3);
    if (tile >= nTiles) return;
    const int m0 = tile * BM;
    const int grow = m0 + wv * 16 + l16;

    f16x8 ah[2][KB], al[2][KB];

    auto loadA = [&](int p, int buf) {
        int i0 = N, i1 = N;
        if (grow < N) {
            i0 = nbr[(size_t)grow * 27 + 2 * p];
            if (2 * p + 1 < 27) i1 = nbr[(size_t)grow * 27 + 2 * p + 1];
        }
        #pragma unroll
        for (int kb = 0; kb < KB; ++kb) {
            int ko = kb * 32 + quad * 8;
            int ts = ko >= 80;
            int c2 = ko - (ts ? 80 : 0);
            const f16* ap = F + (size_t)(ts ? i1 : i0) * RE + c2;
            ah[buf][kb] = *(const f16x8*)ap;
            al[buf][kb] = *(const f16x8*)(ap + 80);
        }
    };

    auto stageB = [&](int p) {
        for (int i = t; i < 80 * CPR; i += 256) {
            int d = i / CPR, cs = i - d * CPR;
            int c = (cs & ~7) | ((cs ^ d) & 7);
            int tp = c / CPT, cc = c - tp * CPT;
            gl_lds16((const char*)WT + (((size_t)d * 28 + 2 * p + tp) * RE + cc * 8) * 2,
                     BS + (size_t)i * 16);
        }
    };

    f32x4 acc[5];
    #pragma unroll
    for (int ct = 0; ct < 5; ++ct) acc[ct] = (f32x4){0.f, 0.f, 0.f, 0.f};

    auto compute = [&](int buf) {
        #pragma unroll
        for (int kb = 0; kb < KB; ++kb) {
            int ko = kb * 32 + quad * 8;
            int ts = ko >= 80;
            int c2 = ko - (ts ? 80 : 0);
            int ch = ts * CPT + c2 / 8;
            int chl = ch + 10;
            #pragma unroll
            for (int ct = 0; ct < 5; ++ct) {
                int drow = ct * 16 + l16;
                int sb = (ch & ~7) | ((ch ^ drow) & 7);
                int sbl = (chl & ~7) | ((chl ^ drow) & 7);
                f16x8 bh = *(const f16x8*)(BS + drow * PB + sb * 16);
                f16x8 bl = *(const f16x8*)(BS + drow * PB + sbl * 16);
                acc[ct] = __builtin_amdgcn_mfma_f32_16x16x32_f16(ah[buf][kb], bh, acc[ct], 0, 0, 0);
                acc[ct] = __builtin_amdgcn_mfma_f32_16x16x32_f16(al[buf][kb], bh, acc[ct], 0, 0, 0);
                acc[ct] = __builtin_amdgcn_mfma_f32_16x16x32_f16(ah[buf][kb], bl, acc[ct], 0, 0, 0);
            }
        }
    };

    loadA(0, 0);
    #pragma unroll 1
    for (int p = 0; p < 14; ++p) {
        __syncthreads();
        stageB(p);
        if (p < 13) loadA(p + 1, (p + 1) & 1);
        __syncthreads();
        compute(p & 1);
    }

    // scatter score epilogue: s[nbr[row][tap]] += y[row]·Wsc[26-tap]
    #pragma unroll 1
    for (int tap = 0; tap < 27; ++tap) {
        float q0[4] = {}, q1[4] = {};
        #pragma unroll
        for (int ct = 0; ct < 5; ++ct) {
            float2 w = ((const float2*)Wsc)[(size_t)(26 - tap) * 80 + ct * 16 + l16];
            #pragma unroll
            for (int r = 0; r < 4; ++r) { q0[r] += acc[ct][r] * w.x; q1[r] += acc[ct][r] * w.y; }
        }
        #pragma unroll
        for (int m = 1; m < 16; m <<= 1) {
            #pragma unroll
            for (int r = 0; r < 4; ++r) { q0[r] += __shfl_xor(q0[r], m); q1[r] += __shfl_xor(q1[r], m); }
        }
        if (l16 < 8) {
            int r = l16 >> 1, j = l16 & 1;
            float v0 = (r == 0) ? q0[0] : (r == 1) ? q0[1] : (r == 2) ? q0[2] : q0[3];
            float v1 = (r == 0) ? q1[0] : (r == 1) ? q1[1] : (r == 2) ? q1[2] : q1[3];
            float v = (j == 0) ? v0 : v1;
            int row = m0 + wv * 16 + quad * 4 + r;
            if (row < N) {
                int idx = nbr[(size_t)row * 27 + tap];
                if (idx < N)                    // guard: sentinel atomics serialize!
                    atomicAdd(&sout[(size_t)idx * 2 + j], v);
            }
        }
    }
}

// ===========================================================================
// Level 2 (7% density x ~16% mask -> ~1% active taps): wave-per-row fp32.
// Computes y2 row only over active taps (exact: skipped rows are exactly 0),
// then scatters s2 += y2·W2s[26-t] into valid neighbors (symmetric identity).
// ===========================================================================
__global__ __launch_bounds__(256) void lvl2_kernel(
    const float* __restrict__ feat2, const int* __restrict__ nbr2,
    const float* __restrict__ act, const float* __restrict__ W2,
    const float* __restrict__ W2s, float* __restrict__ s2, int N)
{
    int wid = (blockIdx.x * 256 + threadIdx.x) >> 6;
    int lane = threadIdx.x & 63;
    if (wid >= N) return;
    const int n = wid;

    int ld = N;
    if (lane < 27) ld = nbr2[(size_t)n * 27 + lane];
    bool valid = (lane < 27) && (ld < N);
    float a = valid ? act[ld] : 0.f;
    unsigned long long actm = __ballot(a != 0.f);
    if (actm == 0ull) return;                 // y2 row exactly zero
    unsigned long long vmask = __ballot(valid);

    const int c = lane;
    float acc = 0.f;
    unsigned long long m = actm;
    while (m) {
        int t = __ffsll((unsigned long long)m) - 1; m &= m - 1;
        int idx = __shfl(ld, t);
        const float4* f4 = (const float4*)(feat2 + (size_t)idx * 48);
        const float* w = W2 + (size_t)t * 48 * 48;
        #pragma unroll
        for (int q = 0; q < 12; ++q) {
            float4 fv = f4[q];                 // uniform address -> broadcast
            if (c < 48) {
                acc += fv.x * w[(4 * q + 0) * 48 + c];
                acc += fv.y * w[(4 * q + 1) * 48 + c];
                acc += fv.z * w[(4 * q + 2) * 48 + c];
                acc += fv.w * w[(4 * q + 3) * 48 + c];
            }
        }
    }

    m = vmask;
    while (m) {
        int t = __ffsll((unsigned long long)m) - 1; m &= m - 1;
        int idx = __shfl(ld, t);
        float p0 = 0.f, p1 = 0.f;
        if (c < 48) {
            float2 w = ((const float2*)W2s)[(size_t)(26 - t) * 48 + c];
            p0 = acc * w.x; p1 = acc * w.y;
        }
        #pragma unroll
        for (int s = 32; s; s >>= 1) { p0 += __shfl_down(p0, s); p1 += __shfl_down(p1, s); }
        if (lane == 0) {
            atomicAdd(&s2[(size_t)idx * 2 + 0], p0);
            atomicAdd(&s2[(size_t)idx * 2 + 1], p1);
        }
    }
}

// ===========================================================================
// Level 3 (0.1% density): wave-per-row fp32. z = conv(feat3 gated by mask2),
// then points = conv(z) gated by z-nonzero flags. Most rows write zeros.
// ===========================================================================
__global__ __launch_bounds__(256) void lvl3_z_kernel(
    const float* __restrict__ feat3, const int* __restrict__ nbr3,
    const float* __restrict__ act, const float* __restrict__ W3,
    float* __restrict__ z, int* __restrict__ zflag, int N)
{
    int wid = (blockIdx.x * 256 + threadIdx.x) >> 6;
    int lane = threadIdx.x & 63;
    if (wid >= N) return;
    const int n = wid;

    int ld = N;
    if (lane < 27) ld = nbr3[(size_t)n * 27 + lane];
    bool valid = (lane < 27) && (ld < N);
    float a = valid ? act[ld] : 0.f;
    unsigned long long actm = __ballot(a != 0.f);

    const int c = lane;
    float acc = 0.f;
    unsigned long long m = actm;
    while (m) {
        int t = __ffsll((unsigned long long)m) - 1; m &= m - 1;
        int idx = __shfl(ld, t);
        const float4* f4 = (const float4*)(feat3 + (size_t)idx * 16);
        const float* w = W3 + (size_t)t * 256;
        #pragma unroll
        for (int q = 0; q < 4; ++q) {
            float4 fv = f4[q];
            if (c < 16) {
                acc += fv.x * w[(4 * q + 0) * 16 + c];
                acc += fv.y * w[(4 * q + 1) * 16 + c];
                acc += fv.z * w[(4 * q + 2) * 16 + c];
                acc += fv.w * w[(4 * q + 3) * 16 + c];
            }
        }
    }
    if (lane < 16) z[(size_t)n * 16 + lane] = acc;
    if (lane == 0) zflag[n] = (actm != 0ull) ? 1 : 0;
}

__global__ __launch_bounds__(256) void lvl3_pts_kernel(
    const float* __restrict__ z, const int* __restrict__ zflag,
    const int* __restrict__ nbr3,
    const float* __restrict__ Wp, const float* __restrict__ Ws,
    const float* __restrict__ Wt, float* __restrict__ points, int N)
{
    int wid = (blockIdx.x * 256 + threadIdx.x) >> 6;
    int lane = threadIdx.x & 63;
    if (wid >= N) return;
    const int n = wid;

    int ld = N;
    if (lane < 27) ld = nbr3[(size_t)n * 27 + lane];
    bool valid = (lane < 27) && (ld < N);
    int zf = valid ? zflag[ld] : 0;
    unsigned long long actm = __ballot(zf != 0);

    const int c = lane;
    float acc = 0.f;
    unsigned long long m = actm;
    while (m) {
        int t = __ffsll((unsigned long long)m) - 1; m &= m - 1;
        int idx = __shfl(ld, t);
        const float4* z4 = (const float4*)(z + (size_t)idx * 16);
        #pragma unroll
        for (int q = 0; q < 4; ++q) {
            float4 zv = z4[q];
            if (c < 10) {
                #pragma unroll
                for (int j = 0; j < 4; ++j) {
                    int k = 4 * q + j;
                    int kc = t * 16 + k;
                    float wv = (c < 3) ? Wp[(size_t)kc * 3 + c]
                             : (c < 5) ? Ws[(size_t)kc * 2 + (c - 3)]
                                       : Wt[(size_t)kc * 5 + (c - 5)];
                    float zj = (j == 0) ? zv.x : (j == 1) ? zv.y : (j == 2) ? zv.z : zv.w;
                    acc += zj * wv;
                }
            }
        }
    }
    if (lane < 10) points[(size_t)n * 10 + lane] = acc;
}

// ===========================================================================
extern "C" void kernel_launch(void* const* d_in, const int* in_sizes, int n_in,
                              void* d_out, int out_size, void* d_ws, size_t ws_size,
                              hipStream_t stream)
{
    const float* feat1 = (const float*)d_in[0];
    const float* feat2 = (const float*)d_in[1];
    const float* feat3 = (const float*)d_in[2];
    const float* W1    = (const float*)d_in[3];
    const float* W1s   = (const float*)d_in[4];
    const float* W2    = (const float*)d_in[5];
    const float* W2s   = (const float*)d_in[6];
    const float* W3    = (const float*)d_in[7];
    const float* W3p   = (const float*)d_in[8];
    const float* W3s   = (const float*)d_in[9];
    const float* W3t   = (const float*)d_in[10];
    const int* nbr1    = (const int*)d_in[11];
    const int* nbr2    = (const int*)d_in[12];
    const int* nbr3    = (const int*)d_in[13];
    const int* parent2 = (const int*)d_in[14];
    const int* parent3 = (const int*)d_in[15];
    const int* coords1 = (const int*)d_in[16];
    const int* coords2 = (const int*)d_in[17];

    const int N1 = in_sizes[0] / 80;
    const int N2 = in_sizes[1] / 48;
    const int N3 = in_sizes[2] / 16;

    float* out = (float*)d_out;
    float* o_points = out;                              // [N3,10]
    float* o_ppn1   = o_points + (size_t)N3 * 10;       // [N1,6]
    float* o_ppn2   = o_ppn1 + (size_t)N1 * 6;          // [N2,6]
    float* o_mask1  = o_ppn2 + (size_t)N2 * 6;          // [N1]
    float* o_mask2  = o_mask1 + (size_t)N1;             // [N2]

    char* wp = (char*)d_ws;
    auto alloc = [&](size_t bytes) -> char* {
        char* r = wp; wp += (bytes + 255) & ~(size_t)255; return r;
    };
    f16*   WT1   = (f16*)alloc((size_t)80 * 28 * 160 * 2);
    f16*   Fa    = (f16*)alloc((size_t)(N1 + 1) * 160 * 2);
    float* s1    = (float*)alloc((size_t)(N1 + 1) * 2 * 4);
    float* s2    = (float*)alloc((size_t)(N2 + 1) * 2 * 4);
    float* act2  = (float*)alloc((size_t)N2 * 4);
    float* act3  = (float*)alloc((size_t)N3 * 4);
    float* zbuf  = (float*)alloc((size_t)N3 * 16 * 4);
    int*   zflag = (int*)alloc((size_t)N3 * 4);

    auto cdiv = [](long long a, long long b) { return (int)((a + b - 1) / b); };

    // ---- level 1: dense MFMA conv80 + fused scatter score ----
    prep_w1_kernel<<<700, 256, 0, stream>>>(W1, WT1);
    split80_kernel<<<cdiv((size_t)(N1 + 1) * 80, 256), 256, 0, stream>>>(feat1, Fa, N1);
    hipMemsetAsync(s1, 0, (size_t)(N1 + 1) * 2 * sizeof(float), stream);
    {
        int T = cdiv(N1, 64);
        dim3 grid(8 * cdiv(T, 8));
        conv80_scat<<<grid, 256, 0, stream>>>(Fa, nbr1, WT1, W1s, s1, N1, T);
    }
    ppn_finalize_kernel<<<cdiv(N1, 256), 256, 0, stream>>>(coords1, s1, o_ppn1, o_mask1, N1);

    // ---- level 2: sparse fp32 wave-per-row, fused scatter score ----
    gate_kernel<<<cdiv(N2, 256), 256, 0, stream>>>(o_mask1, parent2, act2, N2);
    hipMemsetAsync(s2, 0, (size_t)(N2 + 1) * 2 * sizeof(float), stream);
    lvl2_kernel<<<cdiv(N2, 4), 256, 0, stream>>>(feat2, nbr2, act2, W2, W2s, s2, N2);
    ppn_finalize_kernel<<<cdiv(N2, 256), 256, 0, stream>>>(coords2, s2, o_ppn2, o_mask2, N2);

    // ---- level 3: sparse fp32 wave-per-row, z then points ----
    gate_kernel<<<cdiv(N3, 256), 256, 0, stream>>>(o_mask2, parent3, act3, N3);
    lvl3_z_kernel<<<cdiv(N3, 4), 256, 0, stream>>>(feat3, nbr3, act3, W3, zbuf, zflag, N3);
    lvl3_pts_kernel<<<cdiv(N3, 4), 256, 0, stream>>>(zbuf, zflag, nbr3, W3p, W3s, W3t, o_points, N3);
}

// Round 9
// 422.951 us; speedup vs baseline: 1.1774x; 1.0053x over previous
//
#include <hip/hip_runtime.h>

typedef _Float16 f16;
typedef _Float16 f16x8 __attribute__((ext_vector_type(8)));
typedef float f32x4 __attribute__((ext_vector_type(4)));

#define LN4 1.3862943611198906f

__device__ __forceinline__ void gl_lds16(const void* g, void* l) {
    typedef unsigned int u32;
    __builtin_amdgcn_global_load_lds(
        (const __attribute__((address_space(1))) u32*)(g),
        (__attribute__((address_space(3))) u32*)(l), 16, 0, 0);
}

// ===========================================================================
// Level-1 weight prep: fp32 W1[27][80][80] -> f16 hi/lo transposed:
// WT[d][tap][ h(80) | l(80) ], d<80, tap<28 (tap 27 = zeros).
// ===========================================================================
__global__ __launch_bounds__(256) void prep_w1_kernel(
    const float* __restrict__ W, f16* __restrict__ dst)
{
    const int CIN = 80, COUT = 80;
    int total = COUT * 28 * CIN;
    for (int i = blockIdx.x * 256 + threadIdx.x; i < total; i += gridDim.x * 256) {
        int d = i / (28 * CIN);
        int rem = i - d * (28 * CIN);
        int tap = rem / CIN;
        int c = rem - tap * CIN;
        float v = (tap < 27) ? W[(size_t)(tap * CIN + c) * COUT + d] : 0.f;
        f16 h = (f16)v;
        size_t base = (size_t)d * (28 * 2 * CIN) + (size_t)tap * (2 * CIN);
        dst[base + c] = h;
        dst[base + CIN + c] = (f16)(v - (float)h);
    }
}

// Level-1 feature split: rows [h(80)|l(80)] f16, zero-sentinel row at n==N.
__global__ __launch_bounds__(256) void split80_kernel(
    const float* __restrict__ f, f16* __restrict__ Fc, int N)
{
    int i = blockIdx.x * 256 + threadIdx.x;
    if (i >= (N + 1) * 80) return;
    int n = i / 80, c = i - n * 80;
    float v = (n < N) ? f[i] : 0.f;
    f16 h = (f16)v;
    Fc[(size_t)n * 160 + c] = h;
    Fc[(size_t)n * 160 + 80 + c] = (f16)(v - (float)h);
}

__global__ __launch_bounds__(256) void ppn_finalize_kernel(
    const int* __restrict__ coords, const float* __restrict__ s,
    float* __restrict__ ppn, float* __restrict__ mask, int N)
{
    int n = blockIdx.x * 256 + threadIdx.x;
    if (n >= N) return;
    float s0 = s[(size_t)n * 2 + 0], s1 = s[(size_t)n * 2 + 1];
    ppn[(size_t)n * 6 + 0] = (float)coords[(size_t)n * 4 + 0];
    ppn[(size_t)n * 6 + 1] = (float)coords[(size_t)n * 4 + 1];
    ppn[(size_t)n * 6 + 2] = (float)coords[(size_t)n * 4 + 2];
    ppn[(size_t)n * 6 + 3] = (float)coords[(size_t)n * 4 + 3];
    ppn[(size_t)n * 6 + 4] = s0;
    ppn[(size_t)n * 6 + 5] = s1;
    mask[n] = (s1 - s0 > LN4) ? 1.0f : 0.0f;
}

// act[i] = mask[parent[i]]
__global__ __launch_bounds__(256) void gate_kernel(
    const float* __restrict__ mask, const int* __restrict__ parent,
    float* __restrict__ act, int N)
{
    int i = blockIdx.x * 256 + threadIdx.x;
    if (i < N) act[i] = mask[parent[i]];
}

// flag[nbr[m][t]] = 1 for every active source m (nbr symmetry => exact
// "row n has >=1 active neighbor" indicator). FSRC: float src, else int src.
template<bool FSRC>
__global__ __launch_bounds__(256) void expand_kernel(
    const void* __restrict__ src, const int* __restrict__ nbr,
    int* __restrict__ flag, int N)
{
    int m = blockIdx.x * 256 + threadIdx.x;
    if (m >= N) return;
    bool a = FSRC ? (((const float*)src)[m] != 0.f) : (((const int*)src)[m] != 0);
    if (!a) return;
    #pragma unroll 1
    for (int t = 0; t < 27; ++t) {
        int idx = nbr[(size_t)m * 27 + t];
        if (idx < N) flag[idx] = 1;
    }
}

// wave-aggregated compaction: list[0..cnt) = rows with flag!=0
__global__ __launch_bounds__(256) void compact_kernel(
    const int* __restrict__ flag, int* __restrict__ list,
    int* __restrict__ cnt, int N)
{
    int i = blockIdx.x * 256 + threadIdx.x;
    int lane = threadIdx.x & 63;
    bool f = (i < N) && (flag[i] != 0);
    unsigned long long m = __ballot(f);
    int base = 0;
    if (lane == 0 && m) base = atomicAdd(cnt, __popcll(m));
    base = __shfl(base, 0);
    if (f) list[base + __popcll(m & ((1ull << lane) - 1ull))] = i;
}

// ===========================================================================
// Level 1: MFMA conv80 (f16-split, 3-term) fused with scatter score conv.
// (R5-measured structure, unchanged.)
// ===========================================================================
__global__ __launch_bounds__(256, 3) void conv80_scat(
    const f16* __restrict__ F, const int* __restrict__ nbr,
    const f16* __restrict__ WT, const float* __restrict__ Wsc,
    float* __restrict__ sout, int N, int nTiles)
{
    constexpr int RE = 160, CPT = 20, CPR = 40, PB = 640, KB = 5, BM = 64;
    __shared__ __align__(16) char BS[80 * PB];     // 51200 B

    const int t = threadIdx.x;
    const int lane = t & 63;
    const int l16 = lane & 15;
    const int quad = lane >> 4;
    const int wv = t >> 6;

    int q8 = (nTiles + 7) >> 3;
    int tile = (blockIdx.x & 7) * q8 + (blockIdx.x >> 3);
    if (tile >= nTiles) return;
    const int m0 = tile * BM;
    const int grow = m0 + wv * 16 + l16;

    f16x8 ah[2][KB], al[2][KB];

    auto loadA = [&](int p, int buf) {
        int i0 = N, i1 = N;
        if (grow < N) {
            i0 = nbr[(size_t)grow * 27 + 2 * p];
            if (2 * p + 1 < 27) i1 = nbr[(size_t)grow * 27 + 2 * p + 1];
        }
        #pragma unroll
        for (int kb = 0; kb < KB; ++kb) {
            int ko = kb * 32 + quad * 8;
            int ts = ko >= 80;
            int c2 = ko - (ts ? 80 : 0);
            const f16* ap = F + (size_t)(ts ? i1 : i0) * RE + c2;
            ah[buf][kb] = *(const f16x8*)ap;
            al[buf][kb] = *(const f16x8*)(ap + 80);
        }
    };

    auto stageB = [&](int p) {
        for (int i = t; i < 80 * CPR; i += 256) {
            int d = i / CPR, cs = i - d * CPR;
            int c = (cs & ~7) | ((cs ^ d) & 7);
            int tp = c / CPT, cc = c - tp * CPT;
            gl_lds16((const char*)WT + (((size_t)d * 28 + 2 * p + tp) * RE + cc * 8) * 2,
                     BS + (size_t)i * 16);
        }
    };

    f32x4 acc[5];
    #pragma unroll
    for (int ct = 0; ct < 5; ++ct) acc[ct] = (f32x4){0.f, 0.f, 0.f, 0.f};

    auto compute = [&](int buf) {
        #pragma unroll
        for (int kb = 0; kb < KB; ++kb) {
            int ko = kb * 32 + quad * 8;
            int ts = ko >= 80;
            int c2 = ko - (ts ? 80 : 0);
            int ch = ts * CPT + c2 / 8;
            int chl = ch + 10;
            #pragma unroll
            for (int ct = 0; ct < 5; ++ct) {
                int drow = ct * 16 + l16;
                int sb = (ch & ~7) | ((ch ^ drow) & 7);
                int sbl = (chl & ~7) | ((chl ^ drow) & 7);
                f16x8 bh = *(const f16x8*)(BS + drow * PB + sb * 16);
                f16x8 bl = *(const f16x8*)(BS + drow * PB + sbl * 16);
                acc[ct] = __builtin_amdgcn_mfma_f32_16x16x32_f16(ah[buf][kb], bh, acc[ct], 0, 0, 0);
                acc[ct] = __builtin_amdgcn_mfma_f32_16x16x32_f16(al[buf][kb], bh, acc[ct], 0, 0, 0);
                acc[ct] = __builtin_amdgcn_mfma_f32_16x16x32_f16(ah[buf][kb], bl, acc[ct], 0, 0, 0);
            }
        }
    };

    loadA(0, 0);
    #pragma unroll 1
    for (int p = 0; p < 14; ++p) {
        __syncthreads();
        stageB(p);
        if (p < 13) loadA(p + 1, (p + 1) & 1);
        __syncthreads();
        compute(p & 1);
    }

    #pragma unroll 1
    for (int tap = 0; tap < 27; ++tap) {
        float q0[4] = {}, q1[4] = {};
        #pragma unroll
        for (int ct = 0; ct < 5; ++ct) {
            float2 w = ((const float2*)Wsc)[(size_t)(26 - tap) * 80 + ct * 16 + l16];
            #pragma unroll
            for (int r = 0; r < 4; ++r) { q0[r] += acc[ct][r] * w.x; q1[r] += acc[ct][r] * w.y; }
        }
        #pragma unroll
        for (int m = 1; m < 16; m <<= 1) {
            #pragma unroll
            for (int r = 0; r < 4; ++r) { q0[r] += __shfl_xor(q0[r], m); q1[r] += __shfl_xor(q1[r], m); }
        }
        if (l16 < 8) {
            int r = l16 >> 1, j = l16 & 1;
            float v0 = (r == 0) ? q0[0] : (r == 1) ? q0[1] : (r == 2) ? q0[2] : q0[3];
            float v1 = (r == 0) ? q1[0] : (r == 1) ? q1[1] : (r == 2) ? q1[2] : q1[3];
            float v = (j == 0) ? v0 : v1;
            int row = m0 + wv * 16 + quad * 4 + r;
            if (row < N) {
                int idx = nbr[(size_t)row * 27 + tap];
                if (idx < N)                    // guard: sentinel atomics serialize!
                    atomicAdd(&sout[(size_t)idx * 2 + j], v);
            }
        }
    }
}

// ===========================================================================
// Level 2 compute: persistent waves over compacted active-row list.
// ===========================================================================
__global__ __launch_bounds__(256) void lvl2_compute(
    const float* __restrict__ feat2, const int* __restrict__ nbr2,
    const float* __restrict__ act, const float* __restrict__ W2,
    const float* __restrict__ W2s, float* __restrict__ s2,
    const int* __restrict__ list, const int* __restrict__ cnt, int N)
{
    const int lane = threadIdx.x & 63;
    const int wid0 = (blockIdx.x * 256 + threadIdx.x) >> 6;
    const int nw = (gridDim.x * 256) >> 6;
    const int count = *cnt;
    const int c = lane;

    for (int w = wid0; w < count; w += nw) {
        const int n = list[w];
        int ld = N;
        if (lane < 27) ld = nbr2[(size_t)n * 27 + lane];
        bool valid = (lane < 27) && (ld < N);
        float a = valid ? act[ld] : 0.f;
        unsigned long long actm = __ballot(a != 0.f);
        unsigned long long vmask = __ballot(valid);

        float acc = 0.f;
        unsigned long long m = actm;
        while (m) {
            int t = __ffsll(m) - 1; m &= m - 1;
            int idx = __shfl(ld, t);
            const float4* f4 = (const float4*)(feat2 + (size_t)idx * 48);
            const float* wgt = W2 + (size_t)t * 48 * 48;
            #pragma unroll
            for (int q = 0; q < 12; ++q) {
                float4 fv = f4[q];                 // uniform address -> broadcast
                if (c < 48) {
                    acc += fv.x * wgt[(4 * q + 0) * 48 + c];
                    acc += fv.y * wgt[(4 * q + 1) * 48 + c];
                    acc += fv.z * wgt[(4 * q + 2) * 48 + c];
                    acc += fv.w * wgt[(4 * q + 3) * 48 + c];
                }
            }
        }

        m = vmask;
        while (m) {
            int t = __ffsll(m) - 1; m &= m - 1;
            int idx = __shfl(ld, t);
            float p0 = 0.f, p1 = 0.f;
            if (c < 48) {
                float2 wv2 = ((const float2*)W2s)[(size_t)(26 - t) * 48 + c];
                p0 = acc * wv2.x; p1 = acc * wv2.y;
            }
            #pragma unroll
            for (int s = 32; s; s >>= 1) { p0 += __shfl_down(p0, s); p1 += __shfl_down(p1, s); }
            if (lane == 0) {
                atomicAdd(&s2[(size_t)idx * 2 + 0], p0);
                atomicAdd(&s2[(size_t)idx * 2 + 1], p1);
            }
        }
    }
}

// ===========================================================================
// Level 3 compute kernels over compacted lists (zbuf / points pre-zeroed).
// ===========================================================================
__global__ __launch_bounds__(256) void lvl3_z_compute(
    const float* __restrict__ feat3, const int* __restrict__ nbr3,
    const float* __restrict__ act, const float* __restrict__ W3,
    float* __restrict__ z, const int* __restrict__ list,
    const int* __restrict__ cnt, int N)
{
    const int lane = threadIdx.x & 63;
    const int wid0 = (blockIdx.x * 256 + threadIdx.x) >> 6;
    const int nw = (gridDim.x * 256) >> 6;
    const int count = *cnt;
    const int c = lane;

    for (int w = wid0; w < count; w += nw) {
        const int n = list[w];
        int ld = N;
        if (lane < 27) ld = nbr3[(size_t)n * 27 + lane];
        bool valid = (lane < 27) && (ld < N);
        float a = valid ? act[ld] : 0.f;
        unsigned long long m = __ballot(a != 0.f);

        float acc = 0.f;
        while (m) {
            int t = __ffsll(m) - 1; m &= m - 1;
            int idx = __shfl(ld, t);
            const float4* f4 = (const float4*)(feat3 + (size_t)idx * 16);
            const float* wgt = W3 + (size_t)t * 256;
            #pragma unroll
            for (int q = 0; q < 4; ++q) {
                float4 fv = f4[q];
                if (c < 16) {
                    acc += fv.x * wgt[(4 * q + 0) * 16 + c];
                    acc += fv.y * wgt[(4 * q + 1) * 16 + c];
                    acc += fv.z * wgt[(4 * q + 2) * 16 + c];
                    acc += fv.w * wgt[(4 * q + 3) * 16 + c];
                }
            }
        }
        if (lane < 16) z[(size_t)n * 16 + lane] = acc;
    }
}

__global__ __launch_bounds__(256) void lvl3_pts_compute(
    const float* __restrict__ z, const int* __restrict__ zflag,
    const int* __restrict__ nbr3,
    const float* __restrict__ Wp, const float* __restrict__ Ws,
    const float* __restrict__ Wt, float* __restrict__ points,
    const int* __restrict__ list, const int* __restrict__ cnt, int N)
{
    const int lane = threadIdx.x & 63;
    const int wid0 = (blockIdx.x * 256 + threadIdx.x) >> 6;
    const int nw = (gridDim.x * 256) >> 6;
    const int count = *cnt;
    const int c = lane;

    for (int w = wid0; w < count; w += nw) {
        const int n = list[w];
        int ld = N;
        if (lane < 27) ld = nbr3[(size_t)n * 27 + lane];
        bool valid = (lane < 27) && (ld < N);
        int zf = valid ? zflag[ld] : 0;
        unsigned long long m = __ballot(zf != 0);

        float acc = 0.f;
        while (m) {
            int t = __ffsll(m) - 1; m &= m - 1;
            int idx = __shfl(ld, t);
            const float4* z4 = (const float4*)(z + (size_t)idx * 16);
            #pragma unroll
            for (int q = 0; q < 4; ++q) {
                float4 zv = z4[q];
                if (c < 10) {
                    #pragma unroll
                    for (int j = 0; j < 4; ++j) {
                        int k = 4 * q + j;
                        int kc = t * 16 + k;
                        float wv = (c < 3) ? Wp[(size_t)kc * 3 + c]
                                 : (c < 5) ? Ws[(size_t)kc * 2 + (c - 3)]
                                           : Wt[(size_t)kc * 5 + (c - 5)];
                        float zj = (j == 0) ? zv.x : (j == 1) ? zv.y : (j == 2) ? zv.z : zv.w;
                        acc += zj * wv;
                    }
                }
            }
        }
        if (lane < 10) points[(size_t)n * 10 + lane] = acc;
    }
}

// ===========================================================================
extern "C" void kernel_launch(void* const* d_in, const int* in_sizes, int n_in,
                              void* d_out, int out_size, void* d_ws, size_t ws_size,
                              hipStream_t stream)
{
    const float* feat1 = (const float*)d_in[0];
    const float* feat2 = (const float*)d_in[1];
    const float* feat3 = (const float*)d_in[2];
    const float* W1    = (const float*)d_in[3];
    const float* W1s   = (const float*)d_in[4];
    const float* W2    = (const float*)d_in[5];
    const float* W2s   = (const float*)d_in[6];
    const float* W3    = (const float*)d_in[7];
    const float* W3p   = (const float*)d_in[8];
    const float* W3s   = (const float*)d_in[9];
    const float* W3t   = (const float*)d_in[10];
    const int* nbr1    = (const int*)d_in[11];
    const int* nbr2    = (const int*)d_in[12];
    const int* nbr3    = (const int*)d_in[13];
    const int* parent2 = (const int*)d_in[14];
    const int* parent3 = (const int*)d_in[15];
    const int* coords1 = (const int*)d_in[16];
    const int* coords2 = (const int*)d_in[17];

    const int N1 = in_sizes[0] / 80;
    const int N2 = in_sizes[1] / 48;
    const int N3 = in_sizes[2] / 16;

    float* out = (float*)d_out;
    float* o_points = out;                              // [N3,10]
    float* o_ppn1   = o_points + (size_t)N3 * 10;       // [N1,6]
    float* o_ppn2   = o_ppn1 + (size_t)N1 * 6;          // [N2,6]
    float* o_mask1  = o_ppn2 + (size_t)N2 * 6;          // [N1]
    float* o_mask2  = o_mask1 + (size_t)N1;             // [N2]

    char* wp = (char*)d_ws;
    auto alloc = [&](size_t bytes) -> char* {
        char* r = wp; wp += (bytes + 255) & ~(size_t)255; return r;
    };
    f16*   WT1   = (f16*)alloc((size_t)80 * 28 * 160 * 2);
    f16*   Fa    = (f16*)alloc((size_t)(N1 + 1) * 160 * 2);
    float* s1    = (float*)alloc((size_t)(N1 + 1) * 2 * 4);
    float* s2    = (float*)alloc((size_t)(N2 + 1) * 2 * 4);
    float* act2  = (float*)alloc((size_t)N2 * 4);
    float* act3  = (float*)alloc((size_t)N3 * 4);
    int*   flag2 = (int*)alloc((size_t)N2 * 4);
    int*   list2 = (int*)alloc((size_t)N2 * 4);
    int*   flagz = (int*)alloc((size_t)N3 * 4);
    int*   listz = (int*)alloc((size_t)N3 * 4);
    int*   flagp = (int*)alloc((size_t)N3 * 4);
    int*   listp = (int*)alloc((size_t)N3 * 4);
    float* zbuf  = (float*)alloc((size_t)N3 * 16 * 4);
    int*   cnts  = (int*)alloc(3 * 4);    // [cnt2, cntz, cntp]

    auto cdiv = [](long long a, long long b) { return (int)((a + b - 1) / b); };

    // zero the accumulators / flags / compacted counters / zero-default outputs
    hipMemsetAsync(s1, 0, (size_t)(N1 + 1) * 2 * 4, stream);
    hipMemsetAsync(s2, 0, (size_t)(N2 + 1) * 2 * 4, stream);
    hipMemsetAsync(flag2, 0, (size_t)N2 * 4, stream);
    hipMemsetAsync(flagz, 0, (size_t)N3 * 4, stream);
    hipMemsetAsync(flagp, 0, (size_t)N3 * 4, stream);
    hipMemsetAsync(zbuf, 0, (size_t)N3 * 16 * 4, stream);
    hipMemsetAsync(cnts, 0, 3 * 4, stream);
    hipMemsetAsync(o_points, 0, (size_t)N3 * 10 * 4, stream);

    // ---- level 1: dense MFMA conv80 + fused scatter score ----
    prep_w1_kernel<<<700, 256, 0, stream>>>(W1, WT1);
    split80_kernel<<<cdiv((size_t)(N1 + 1) * 80, 256), 256, 0, stream>>>(feat1, Fa, N1);
    {
        int T = cdiv(N1, 64);
        dim3 grid(8 * cdiv(T, 8));
        conv80_scat<<<grid, 256, 0, stream>>>(Fa, nbr1, WT1, W1s, s1, N1, T);
    }
    ppn_finalize_kernel<<<cdiv(N1, 256), 256, 0, stream>>>(coords1, s1, o_ppn1, o_mask1, N1);

    // ---- level 2: expand -> compact -> persistent sparse compute ----
    gate_kernel<<<cdiv(N2, 256), 256, 0, stream>>>(o_mask1, parent2, act2, N2);
    expand_kernel<true><<<cdiv(N2, 256), 256, 0, stream>>>(act2, nbr2, flag2, N2);
    compact_kernel<<<cdiv(N2, 256), 256, 0, stream>>>(flag2, list2, &cnts[0], N2);
    lvl2_compute<<<2048, 256, 0, stream>>>(feat2, nbr2, act2, W2, W2s, s2,
                                           list2, &cnts[0], N2);
    ppn_finalize_kernel<<<cdiv(N2, 256), 256, 0, stream>>>(coords2, s2, o_ppn2, o_mask2, N2);

    // ---- level 3: two-hop expand/compact, z then points ----
    gate_kernel<<<cdiv(N3, 256), 256, 0, stream>>>(o_mask2, parent3, act3, N3);
    expand_kernel<true><<<cdiv(N3, 256), 256, 0, stream>>>(act3, nbr3, flagz, N3);
    compact_kernel<<<cdiv(N3, 256), 256, 0, stream>>>(flagz, listz, &cnts[1], N3);
    lvl3_z_compute<<<2048, 256, 0, stream>>>(feat3, nbr3, act3, W3, zbuf,
                                             listz, &cnts[1], N3);
    expand_kernel<false><<<cdiv(N3, 256), 256, 0, stream>>>(flagz, nbr3, flagp, N3);
    compact_kernel<<<cdiv(N3, 256), 256, 0, stream>>>(flagp, listp, &cnts[2], N3);
    lvl3_pts_compute<<<2048, 256, 0, stream>>>(zbuf, flagz, nbr3, W3p, W3s, W3t,
                                               o_points, listp, &cnts[2], N3);
}